// Round 2
// baseline (2682.119 us; speedup 1.0000x reference)
//
#include <hip/hip_runtime.h>

// DeformConv3D forward, fp32. B=2, C=Cout=64, D=8, H=56, W=56, K=27,
// stride=pad=dil=1, deform_groups=1, groups=1.
#define CIN  64
#define COUT 64
#define DD   8
#define HH   56
#define WWID 56
#define KK   27
#define PP   (DD * HH * WWID)   // 25088
#define BB   2

// ---------- weight transpose: w[co][c][k] -> wT[k][c][co] ----------
__global__ __launch_bounds__(256) void transpose_w_kernel(
    const float* __restrict__ w, float* __restrict__ wT)
{
    int idx = blockIdx.x * 256 + threadIdx.x;
    if (idx >= COUT * CIN * KK) return;
    int k  = idx % KK;
    int t  = idx / KK;
    int c  = t % CIN;
    int co = t / CIN;
    wT[(k * CIN + c) * COUT + co] = w[idx];
}

// ---------- x transpose: x[b][c][p] -> xT[b][p][c] (channel-last) ----------
// 64x64 tile through LDS, padded stride 65 (bank-conflict free).
__global__ __launch_bounds__(256) void transpose_x_kernel(
    const float* __restrict__ x, float* __restrict__ xT)
{
    __shared__ float tile[64 * 65];
    const int b  = blockIdx.x / (PP / 64);
    const int p0 = (blockIdx.x % (PP / 64)) * 64;
    const int tid = threadIdx.x;
    const int lane = tid & 63;
    const int row4 = tid >> 6;          // 0..3

#pragma unroll
    for (int pass = 0; pass < 16; ++pass) {
        const int c = pass * 4 + row4;
        tile[lane * 65 + c] = x[((size_t)b * CIN + c) * PP + p0 + lane];
    }
    __syncthreads();
#pragma unroll
    for (int pass = 0; pass < 16; ++pass) {
        const int pr = pass * 4 + row4;
        xT[((size_t)b * PP + p0 + pr) * 64 + lane] = tile[pr * 65 + lane];
    }
}

__device__ __forceinline__ void fma4(float4& a, const float4 w, const float v) {
    a.x += w.x * v; a.y += w.y * v; a.z += w.z * v; a.w += w.w * v;
}

// ---------- main: thread = (voxel, co-quarter), channel-last gathers ----------
// block 256 = 64 voxels x 4 co-quarters; all 4 waves share one x footprint.
__global__ __launch_bounds__(256, 3) void deform_main_kernel(
    const float* __restrict__ xT, const float* __restrict__ off,
    const float* __restrict__ wT, float* __restrict__ out)
{
    const int tid = threadIdx.x;
    const int quarter = tid >> 6;         // 0..3 -> co 16*quarter..
    const int lv = tid & 63;
    const int vox = blockIdx.x * 64 + lv; // 0..50175
    const int b = vox / PP;
    const int p = vox - b * PP;
    const int wq = p % WWID;
    const int hq = (p / WWID) % HH;
    const int dq = p / (HH * WWID);
    const int co_base = quarter * 16;

    const float* __restrict__ xb   = xT + (size_t)b * PP * 64;
    const float* __restrict__ offb = off + (size_t)b * (3 * KK * PP) + p;

    float4 acc0 = make_float4(0.f, 0.f, 0.f, 0.f);
    float4 acc1 = acc0, acc2 = acc0, acc3 = acc0;

    for (int k = 0; k < KK; ++k) {
        const int kd = k / 9, kh = (k / 3) % 3, kw = k % 3;
        const float od = offb[(k * 3 + 0) * PP];
        const float oh = offb[(k * 3 + 1) * PP];
        const float ow = offb[(k * 3 + 2) * PP];
        const float pd = od + (float)(dq - 1 + kd);
        const float ph = oh + (float)(hq - 1 + kh);
        const float pw = ow + (float)(wq - 1 + kw);
        const float d0f = floorf(pd), h0f = floorf(ph), w0f = floorf(pw);
        const float fd = pd - d0f, fh = ph - h0f, fw = pw - w0f;
        const int d0 = (int)d0f, h0 = (int)h0f, w0 = (int)w0f;
        const int d1 = d0 + 1, h1 = h0 + 1, w1 = w0 + 1;

        const float wd0 = (1.f - fd) * ((d0 >= 0 && d0 < DD) ? 1.f : 0.f);
        const float wd1 = fd        * ((d1 >= 0 && d1 < DD) ? 1.f : 0.f);
        const float wh0 = (1.f - fh) * ((h0 >= 0 && h0 < HH) ? 1.f : 0.f);
        const float wh1 = fh        * ((h1 >= 0 && h1 < HH) ? 1.f : 0.f);
        const float ww0 = (1.f - fw) * ((w0 >= 0 && w0 < WWID) ? 1.f : 0.f);
        const float ww1 = fw        * ((w1 >= 0 && w1 < WWID) ? 1.f : 0.f);

        const int cd0 = min(max(d0, 0), DD - 1),   cd1 = min(max(d1, 0), DD - 1);
        const int ch0 = min(max(h0, 0), HH - 1),   ch1 = min(max(h1, 0), HH - 1);
        const int cw0 = min(max(w0, 0), WWID - 1), cw1 = min(max(w1, 0), WWID - 1);

        const float* bp000 = xb + (size_t)(((cd0 * HH + ch0) * WWID + cw0)) * 64;
        const float* bp001 = xb + (size_t)(((cd0 * HH + ch0) * WWID + cw1)) * 64;
        const float* bp010 = xb + (size_t)(((cd0 * HH + ch1) * WWID + cw0)) * 64;
        const float* bp011 = xb + (size_t)(((cd0 * HH + ch1) * WWID + cw1)) * 64;
        const float* bp100 = xb + (size_t)(((cd1 * HH + ch0) * WWID + cw0)) * 64;
        const float* bp101 = xb + (size_t)(((cd1 * HH + ch0) * WWID + cw1)) * 64;
        const float* bp110 = xb + (size_t)(((cd1 * HH + ch1) * WWID + cw0)) * 64;
        const float* bp111 = xb + (size_t)(((cd1 * HH + ch1) * WWID + cw1)) * 64;

        const float c000 = wd0 * wh0 * ww0;
        const float c001 = wd0 * wh0 * ww1;
        const float c010 = wd0 * wh1 * ww0;
        const float c011 = wd0 * wh1 * ww1;
        const float c100 = wd1 * wh0 * ww0;
        const float c101 = wd1 * wh0 * ww1;
        const float c110 = wd1 * wh1 * ww0;
        const float c111 = wd1 * wh1 * ww1;

        const float* __restrict__ wk = wT + (size_t)(k * CIN) * COUT + co_base;

        for (int ch = 0; ch < 16; ++ch) {
            const float4 f000 = *(const float4*)(bp000 + ch * 4);
            const float4 f001 = *(const float4*)(bp001 + ch * 4);
            const float4 f010 = *(const float4*)(bp010 + ch * 4);
            const float4 f011 = *(const float4*)(bp011 + ch * 4);
            const float4 f100 = *(const float4*)(bp100 + ch * 4);
            const float4 f101 = *(const float4*)(bp101 + ch * 4);
            const float4 f110 = *(const float4*)(bp110 + ch * 4);
            const float4 f111 = *(const float4*)(bp111 + ch * 4);

            float4 v;
            v.x = c000*f000.x + c001*f001.x + c010*f010.x + c011*f011.x
                + c100*f100.x + c101*f101.x + c110*f110.x + c111*f111.x;
            v.y = c000*f000.y + c001*f001.y + c010*f010.y + c011*f011.y
                + c100*f100.y + c101*f101.y + c110*f110.y + c111*f111.y;
            v.z = c000*f000.z + c001*f001.z + c010*f010.z + c011*f011.z
                + c100*f100.z + c101*f101.z + c110*f110.z + c111*f111.z;
            v.w = c000*f000.w + c001*f001.w + c010*f010.w + c011*f011.w
                + c100*f100.w + c101*f101.w + c110*f110.w + c111*f111.w;

            const float* wc = wk + (size_t)(ch * 4) * COUT;  // c = ch*4 .. +3
            {
                const float4* wr = (const float4*)(wc);
                fma4(acc0, wr[0], v.x); fma4(acc1, wr[1], v.x);
                fma4(acc2, wr[2], v.x); fma4(acc3, wr[3], v.x);
            }
            {
                const float4* wr = (const float4*)(wc + COUT);
                fma4(acc0, wr[0], v.y); fma4(acc1, wr[1], v.y);
                fma4(acc2, wr[2], v.y); fma4(acc3, wr[3], v.y);
            }
            {
                const float4* wr = (const float4*)(wc + 2 * COUT);
                fma4(acc0, wr[0], v.z); fma4(acc1, wr[1], v.z);
                fma4(acc2, wr[2], v.z); fma4(acc3, wr[3], v.z);
            }
            {
                const float4* wr = (const float4*)(wc + 3 * COUT);
                fma4(acc0, wr[0], v.w); fma4(acc1, wr[1], v.w);
                fma4(acc2, wr[2], v.w); fma4(acc3, wr[3], v.w);
            }
        }
    }

    float* ob = out + (size_t)b * COUT * PP + (size_t)co_base * PP + p;
    ob[0 * PP]  = acc0.x; ob[1 * PP]  = acc0.y; ob[2 * PP]  = acc0.z; ob[3 * PP]  = acc0.w;
    ob[4 * PP]  = acc1.x; ob[5 * PP]  = acc1.y; ob[6 * PP]  = acc1.z; ob[7 * PP]  = acc1.w;
    ob[8 * PP]  = acc2.x; ob[9 * PP]  = acc2.y; ob[10 * PP] = acc2.z; ob[11 * PP] = acc2.w;
    ob[12 * PP] = acc3.x; ob[13 * PP] = acc3.y; ob[14 * PP] = acc3.z; ob[15 * PP] = acc3.w;
}

// ---------- fallback (round-1 naive) if ws is too small ----------
__global__ __launch_bounds__(128) void deform_fallback_kernel(
    const float* __restrict__ x, const float* __restrict__ off,
    const float* __restrict__ w, float* __restrict__ out)
{
    const int co_half = blockIdx.x / 392;
    const int vox     = (blockIdx.x % 392) * 128 + threadIdx.x;
    const int b  = vox / PP;
    const int p  = vox - b * PP;
    const int wq = p % WWID;
    const int hq = (p / WWID) % HH;
    const int dq = p / (HH * WWID);
    const int co_base = co_half * 32;

    const float* xb   = x + (size_t)b * (CIN * PP);
    const float* offb = off + (size_t)b * (3 * KK * PP) + p;

    float acc[32];
#pragma unroll
    for (int j = 0; j < 32; ++j) acc[j] = 0.f;

    for (int k = 0; k < KK; ++k) {
        const int kd = k / 9, kh = (k / 3) % 3, kw = k % 3;
        const float od = offb[(k * 3 + 0) * PP];
        const float oh = offb[(k * 3 + 1) * PP];
        const float ow = offb[(k * 3 + 2) * PP];
        const float pd = od + (float)(dq - 1 + kd);
        const float ph = oh + (float)(hq - 1 + kh);
        const float pw = ow + (float)(wq - 1 + kw);
        const float d0f = floorf(pd), h0f = floorf(ph), w0f = floorf(pw);
        const float fd = pd - d0f, fh = ph - h0f, fw = pw - w0f;
        const int d0 = (int)d0f, h0 = (int)h0f, w0 = (int)w0f;
        const int d1 = d0 + 1, h1 = h0 + 1, w1 = w0 + 1;
        const float wd0 = (1.f - fd) * ((d0 >= 0 && d0 < DD) ? 1.f : 0.f);
        const float wd1 = fd        * ((d1 >= 0 && d1 < DD) ? 1.f : 0.f);
        const float wh0 = (1.f - fh) * ((h0 >= 0 && h0 < HH) ? 1.f : 0.f);
        const float wh1 = fh        * ((h1 >= 0 && h1 < HH) ? 1.f : 0.f);
        const float ww0 = (1.f - fw) * ((w0 >= 0 && w0 < WWID) ? 1.f : 0.f);
        const float ww1 = fw        * ((w1 >= 0 && w1 < WWID) ? 1.f : 0.f);
        const int cd0 = min(max(d0, 0), DD - 1),   cd1 = min(max(d1, 0), DD - 1);
        const int ch0 = min(max(h0, 0), HH - 1),   ch1 = min(max(h1, 0), HH - 1);
        const int cw0 = min(max(w0, 0), WWID - 1), cw1 = min(max(w1, 0), WWID - 1);
        const int l000 = (cd0 * HH + ch0) * WWID + cw0;
        const int l001 = (cd0 * HH + ch0) * WWID + cw1;
        const int l010 = (cd0 * HH + ch1) * WWID + cw0;
        const int l011 = (cd0 * HH + ch1) * WWID + cw1;
        const int l100 = (cd1 * HH + ch0) * WWID + cw0;
        const int l101 = (cd1 * HH + ch0) * WWID + cw1;
        const int l110 = (cd1 * HH + ch1) * WWID + cw0;
        const int l111 = (cd1 * HH + ch1) * WWID + cw1;
        const float c000 = wd0 * wh0 * ww0, c001 = wd0 * wh0 * ww1;
        const float c010 = wd0 * wh1 * ww0, c011 = wd0 * wh1 * ww1;
        const float c100 = wd1 * wh0 * ww0, c101 = wd1 * wh0 * ww1;
        const float c110 = wd1 * wh1 * ww0, c111 = wd1 * wh1 * ww1;
        for (int c = 0; c < CIN; ++c) {
            const float* xc = xb + (size_t)c * PP;
            float v = c000 * xc[l000] + c001 * xc[l001]
                    + c010 * xc[l010] + c011 * xc[l011]
                    + c100 * xc[l100] + c101 * xc[l101]
                    + c110 * xc[l110] + c111 * xc[l111];
#pragma unroll
            for (int j = 0; j < 32; ++j)
                acc[j] += w[((size_t)(co_base + j) * CIN + c) * KK + k] * v;
        }
    }
    float* ob = out + (size_t)b * (COUT * PP) + (size_t)co_base * PP + p;
#pragma unroll
    for (int j = 0; j < 32; ++j) ob[j * PP] = acc[j];
}

extern "C" void kernel_launch(void* const* d_in, const int* in_sizes, int n_in,
                              void* d_out, int out_size, void* d_ws, size_t ws_size,
                              hipStream_t stream)
{
    const float* x   = (const float*)d_in[0];
    const float* off = (const float*)d_in[1];
    const float* w   = (const float*)d_in[2];
    float* out = (float*)d_out;

    const size_t wt_bytes = (size_t)KK * CIN * COUT * sizeof(float);        // 442368
    const size_t xt_bytes = (size_t)BB * PP * CIN * sizeof(float);          // 12.8 MB
    const size_t need = wt_bytes + xt_bytes;

    if (ws_size >= need) {
        float* wT = (float*)d_ws;
        float* xT = (float*)((char*)d_ws + wt_bytes);
        const int nw = COUT * CIN * KK;
        transpose_w_kernel<<<(nw + 255) / 256, 256, 0, stream>>>(w, wT);
        transpose_x_kernel<<<BB * (PP / 64), 256, 0, stream>>>(x, xT);
        // 50176 voxels / 64 per block = 784 blocks
        deform_main_kernel<<<784, 256, 0, stream>>>(xT, off, wT, out);
    } else {
        deform_fallback_kernel<<<2 * 392, 128, 0, stream>>>(x, off, w, out);
    }
}

// Round 3
// 430.627 us; speedup vs baseline: 6.2284x; 6.2284x over previous
//
#include <hip/hip_runtime.h>

// DeformConv3D forward. B=2, C=Cout=64, D=8, H=56, W=56, K=27,
// stride=pad=dil=1, dg=1, groups=1. Fused interp + bf16 MFMA GEMM.
#define CIN  64
#define COUT 64
#define DD   8
#define HH   56
#define WWID 56
#define KK   27
#define PP   (DD * HH * WWID)   // 25088
#define BB   2
#define NBLK 392                // PP/64 voxel tiles per batch

typedef float  f32x4  __attribute__((ext_vector_type(4)));
typedef __bf16 bf16x8 __attribute__((ext_vector_type(8)));

__device__ __forceinline__ unsigned short f2bf(float f) {
    union { float f; unsigned u; } v; v.f = f;
    unsigned r = v.u + 0x7FFF + ((v.u >> 16) & 1);   // RNE
    return (unsigned short)(r >> 16);
}

// ---------- weight pack: w[co][c][k] -> B-fragment order, bf16 ----------
// wPack[tap][kk][ct][lane][j] holds B[k=kk*32+(lane>>4)*8+j][co=ct*16+(lane&15)]
__global__ __launch_bounds__(256) void pack_w_kernel(
    const float* __restrict__ w, unsigned short* __restrict__ wPack)
{
    int idx = blockIdx.x * 256 + threadIdx.x;
    if (idx >= KK * 2 * 4 * 64 * 8) return;
    const int j    = idx & 7;
    const int lane = (idx >> 3) & 63;
    const int ct   = (idx >> 9) & 3;
    const int kk   = (idx >> 11) & 1;
    const int tap  = idx >> 12;
    const int c  = kk * 32 + (lane >> 4) * 8 + j;
    const int co = ct * 16 + (lane & 15);
    wPack[idx] = f2bf(w[(co * CIN + c) * KK + tap]);
}

// ---------- x transpose: x[b][c][p] -> xT[b][p][c] (channel-last fp32) ----------
__global__ __launch_bounds__(256) void transpose_x_kernel(
    const float* __restrict__ x, float* __restrict__ xT)
{
    __shared__ float tile[64 * 65];
    const int b  = blockIdx.x / NBLK;
    const int p0 = (blockIdx.x % NBLK) * 64;
    const int tid = threadIdx.x;
    const int lane = tid & 63;
    const int row4 = tid >> 6;
#pragma unroll
    for (int pass = 0; pass < 16; ++pass) {
        const int c = pass * 4 + row4;
        tile[lane * 65 + c] = x[((size_t)b * CIN + c) * PP + p0 + lane];
    }
    __syncthreads();
#pragma unroll
    for (int pass = 0; pass < 16; ++pass) {
        const int pr = pass * 4 + row4;
        xT[((size_t)b * PP + p0 + pr) * 64 + lane] = tile[pr * 65 + lane];
    }
}

// ---------- fused main: interp -> LDS cols -> MFMA ----------
__global__ __launch_bounds__(256) void deform_mfma_kernel(
    const float* __restrict__ xT, const float* __restrict__ off,
    const unsigned short* __restrict__ wPack, float* __restrict__ out)
{
    __shared__ unsigned short cols[64 * 72];  // [vox][c], pad 64->72 bf16
    __shared__ float outb[64 * 65];           // [co][vox], pad for store phase

    const int tid  = threadIdx.x;
    const int wave = tid >> 6;
    const int lane = tid & 63;
    const int b    = blockIdx.x / NBLK;
    const int p0   = (blockIdx.x % NBLK) * 64;

    const float* __restrict__ xb   = xT + (size_t)b * PP * 64;
    const float* __restrict__ offb = off + (size_t)b * (3 * KK * PP);

    f32x4 acc[4];
#pragma unroll
    for (int ct = 0; ct < 4; ++ct) acc[ct] = (f32x4){0.f, 0.f, 0.f, 0.f};

    const int m16 = lane & 15, q4 = lane >> 4;

    for (int tap = 0; tap < KK; ++tap) {
        const int kd = tap / 9, kh = (tap / 3) % 3, kw = tap % 3;

        // ---- produce: wave handles vox rows wave*16..+15; lane = channel ----
#pragma unroll 4
        for (int r = 0; r < 16; ++r) {
            const int v = wave * 16 + r;
            const int p = p0 + v;
            const int wq = p % WWID;
            const int hq = (p / WWID) % HH;
            const int dq = p / (HH * WWID);

            const float od = offb[(tap * 3 + 0) * PP + p];
            const float oh = offb[(tap * 3 + 1) * PP + p];
            const float ow = offb[(tap * 3 + 2) * PP + p];
            const float pd = od + (float)(dq - 1 + kd);
            const float ph = oh + (float)(hq - 1 + kh);
            const float pw = ow + (float)(wq - 1 + kw);
            const float d0f = floorf(pd), h0f = floorf(ph), w0f = floorf(pw);
            const float fd = pd - d0f, fh = ph - h0f, fw = pw - w0f;
            const int d0 = (int)d0f, h0 = (int)h0f, w0 = (int)w0f;
            const int d1 = d0 + 1, h1 = h0 + 1, w1 = w0 + 1;

            const float wd0 = (1.f - fd) * ((d0 >= 0 && d0 < DD) ? 1.f : 0.f);
            const float wd1 = fd        * ((d1 >= 0 && d1 < DD) ? 1.f : 0.f);
            const float wh0 = (1.f - fh) * ((h0 >= 0 && h0 < HH) ? 1.f : 0.f);
            const float wh1 = fh        * ((h1 >= 0 && h1 < HH) ? 1.f : 0.f);
            const float ww0 = (1.f - fw) * ((w0 >= 0 && w0 < WWID) ? 1.f : 0.f);
            const float ww1 = fw        * ((w1 >= 0 && w1 < WWID) ? 1.f : 0.f);

            const int cd0 = min(max(d0, 0), DD - 1),   cd1 = min(max(d1, 0), DD - 1);
            const int ch0 = min(max(h0, 0), HH - 1),   ch1 = min(max(h1, 0), HH - 1);
            const int cw0 = min(max(w0, 0), WWID - 1), cw1 = min(max(w1, 0), WWID - 1);

            const float* r000 = xb + (size_t)((cd0 * HH + ch0) * WWID + cw0) * 64;
            const float* r001 = xb + (size_t)((cd0 * HH + ch0) * WWID + cw1) * 64;
            const float* r010 = xb + (size_t)((cd0 * HH + ch1) * WWID + cw0) * 64;
            const float* r011 = xb + (size_t)((cd0 * HH + ch1) * WWID + cw1) * 64;
            const float* r100 = xb + (size_t)((cd1 * HH + ch0) * WWID + cw0) * 64;
            const float* r101 = xb + (size_t)((cd1 * HH + ch0) * WWID + cw1) * 64;
            const float* r110 = xb + (size_t)((cd1 * HH + ch1) * WWID + cw0) * 64;
            const float* r111 = xb + (size_t)((cd1 * HH + ch1) * WWID + cw1) * 64;

            const float c000 = wd0 * wh0 * ww0, c001 = wd0 * wh0 * ww1;
            const float c010 = wd0 * wh1 * ww0, c011 = wd0 * wh1 * ww1;
            const float c100 = wd1 * wh0 * ww0, c101 = wd1 * wh0 * ww1;
            const float c110 = wd1 * wh1 * ww0, c111 = wd1 * wh1 * ww1;

            const float val =
                  c000 * r000[lane] + c001 * r001[lane]
                + c010 * r010[lane] + c011 * r011[lane]
                + c100 * r100[lane] + c101 * r101[lane]
                + c110 * r110[lane] + c111 * r111[lane];

            cols[v * 72 + lane] = f2bf(val);
        }
        __syncthreads();

        // ---- consume: wave w does vox band [16w,16w+16) x all 64 co ----
#pragma unroll
        for (int kk = 0; kk < 2; ++kk) {
            const bf16x8 afrag = *(const bf16x8*)
                (cols + (wave * 16 + m16) * 72 + kk * 32 + q4 * 8);
            const bf16x8* wp = (const bf16x8*)
                (wPack + (size_t)(tap * 2 + kk) * 4 * 64 * 8);
#pragma unroll
            for (int ct = 0; ct < 4; ++ct) {
                const bf16x8 bfrag = wp[ct * 64 + lane];
                acc[ct] = __builtin_amdgcn_mfma_f32_16x16x32_bf16(
                    afrag, bfrag, acc[ct], 0, 0, 0);
            }
        }
        __syncthreads();
    }

    // ---- epilogue: C/D layout col=lane&15 (co), row=q4*4+reg (vox) ----
#pragma unroll
    for (int ct = 0; ct < 4; ++ct) {
#pragma unroll
        for (int reg = 0; reg < 4; ++reg) {
            const int vox = wave * 16 + q4 * 4 + reg;
            const int co  = ct * 16 + m16;
            outb[co * 65 + vox] = acc[ct][reg];
        }
    }
    __syncthreads();

#pragma unroll
    for (int i = 0; i < 16; ++i) {
        const int co = wave * 16 + i;
        out[((size_t)b * COUT + co) * PP + p0 + lane] = outb[co * 65 + lane];
    }
}

// ---------- fallback (round-1 structure) if ws too small ----------
__global__ __launch_bounds__(128) void deform_fallback_kernel(
    const float* __restrict__ x, const float* __restrict__ off,
    const float* __restrict__ w, float* __restrict__ out)
{
    const int co_half = blockIdx.x / 392;
    const int vox     = (blockIdx.x % 392) * 128 + threadIdx.x;
    const int b  = vox / PP;
    const int p  = vox - b * PP;
    const int wq = p % WWID;
    const int hq = (p / WWID) % HH;
    const int dq = p / (HH * WWID);
    const int co_base = co_half * 32;
    const float* xb   = x + (size_t)b * (CIN * PP);
    const float* offb = off + (size_t)b * (3 * KK * PP) + p;
    float acc[32];
#pragma unroll
    for (int j = 0; j < 32; ++j) acc[j] = 0.f;
    for (int k = 0; k < KK; ++k) {
        const int kd = k / 9, kh = (k / 3) % 3, kw = k % 3;
        const float od = offb[(k * 3 + 0) * PP];
        const float oh = offb[(k * 3 + 1) * PP];
        const float ow = offb[(k * 3 + 2) * PP];
        const float pd = od + (float)(dq - 1 + kd);
        const float ph = oh + (float)(hq - 1 + kh);
        const float pw = ow + (float)(wq - 1 + kw);
        const float d0f = floorf(pd), h0f = floorf(ph), w0f = floorf(pw);
        const float fd = pd - d0f, fh = ph - h0f, fw = pw - w0f;
        const int d0 = (int)d0f, h0 = (int)h0f, w0 = (int)w0f;
        const int d1 = d0 + 1, h1 = h0 + 1, w1 = w0 + 1;
        const float wd0 = (1.f - fd) * ((d0 >= 0 && d0 < DD) ? 1.f : 0.f);
        const float wd1 = fd        * ((d1 >= 0 && d1 < DD) ? 1.f : 0.f);
        const float wh0 = (1.f - fh) * ((h0 >= 0 && h0 < HH) ? 1.f : 0.f);
        const float wh1 = fh        * ((h1 >= 0 && h1 < HH) ? 1.f : 0.f);
        const float ww0 = (1.f - fw) * ((w0 >= 0 && w0 < WWID) ? 1.f : 0.f);
        const float ww1 = fw        * ((w1 >= 0 && w1 < WWID) ? 1.f : 0.f);
        const int cd0 = min(max(d0, 0), DD - 1),   cd1 = min(max(d1, 0), DD - 1);
        const int ch0 = min(max(h0, 0), HH - 1),   ch1 = min(max(h1, 0), HH - 1);
        const int cw0 = min(max(w0, 0), WWID - 1), cw1 = min(max(w1, 0), WWID - 1);
        const int l000 = (cd0 * HH + ch0) * WWID + cw0;
        const int l001 = (cd0 * HH + ch0) * WWID + cw1;
        const int l010 = (cd0 * HH + ch1) * WWID + cw0;
        const int l011 = (cd0 * HH + ch1) * WWID + cw1;
        const int l100 = (cd1 * HH + ch0) * WWID + cw0;
        const int l101 = (cd1 * HH + ch0) * WWID + cw1;
        const int l110 = (cd1 * HH + ch1) * WWID + cw0;
        const int l111 = (cd1 * HH + ch1) * WWID + cw1;
        const float c000 = wd0 * wh0 * ww0, c001 = wd0 * wh0 * ww1;
        const float c010 = wd0 * wh1 * ww0, c011 = wd0 * wh1 * ww1;
        const float c100 = wd1 * wh0 * ww0, c101 = wd1 * wh0 * ww1;
        const float c110 = wd1 * wh1 * ww0, c111 = wd1 * wh1 * ww1;
        for (int c = 0; c < CIN; ++c) {
            const float* xc = xb + (size_t)c * PP;
            float v = c000 * xc[l000] + c001 * xc[l001]
                    + c010 * xc[l010] + c011 * xc[l011]
                    + c100 * xc[l100] + c101 * xc[l101]
                    + c110 * xc[l110] + c111 * xc[l111];
#pragma unroll
            for (int j = 0; j < 32; ++j)
                acc[j] += w[((size_t)(co_base + j) * CIN + c) * KK + k] * v;
        }
    }
    float* ob = out + (size_t)b * (COUT * PP) + (size_t)co_base * PP + p;
#pragma unroll
    for (int j = 0; j < 32; ++j) ob[j * PP] = acc[j];
}

extern "C" void kernel_launch(void* const* d_in, const int* in_sizes, int n_in,
                              void* d_out, int out_size, void* d_ws, size_t ws_size,
                              hipStream_t stream)
{
    const float* x   = (const float*)d_in[0];
    const float* off = (const float*)d_in[1];
    const float* w   = (const float*)d_in[2];
    float* out = (float*)d_out;

    const size_t xt_bytes = (size_t)BB * PP * CIN * sizeof(float);      // 12,845,056
    const size_t wp_elems = (size_t)KK * 2 * 4 * 64 * 8;                // 110,592
    const size_t need = xt_bytes + wp_elems * sizeof(unsigned short);

    if (ws_size >= need) {
        float* xT = (float*)d_ws;
        unsigned short* wPack = (unsigned short*)((char*)d_ws + xt_bytes);
        pack_w_kernel<<<(int)((wp_elems + 255) / 256), 256, 0, stream>>>(w, wPack);
        transpose_x_kernel<<<BB * NBLK, 256, 0, stream>>>(x, xT);
        deform_mfma_kernel<<<BB * NBLK, 256, 0, stream>>>(xT, off, wPack, out);
    } else {
        deform_fallback_kernel<<<2 * 392, 128, 0, stream>>>(x, off, w, out);
    }
}

// Round 5
// 255.202 us; speedup vs baseline: 10.5098x; 1.6874x over previous
//
#include <hip/hip_runtime.h>

// DeformConv3D forward. B=2, C=Cout=64, D=8, H=56, W=56, K=27,
// stride=pad=dil=1, dg=1, groups=1. Fused interp + bf16 MFMA GEMM.
// R5: wave-private tap loop (no barriers), typed int4/float4 geometry LDS
//     (fixes R4's alignment UB), float4-granularity gathers.
#define CIN  64
#define COUT 64
#define DD   8
#define HH   56
#define WWID 56
#define KK   27
#define PP   (DD * HH * WWID)   // 25088
#define BB   2
#define NBLK 392                // PP/64 voxel tiles per batch

typedef float  f32x4  __attribute__((ext_vector_type(4)));
typedef __bf16 bf16x8 __attribute__((ext_vector_type(8)));
typedef unsigned short u16x4 __attribute__((ext_vector_type(4)));

__device__ __forceinline__ unsigned short f2bf(float f) {
    union { float f; unsigned u; } v; v.f = f;
    unsigned r = v.u + 0x7FFF + ((v.u >> 16) & 1);   // RNE
    return (unsigned short)(r >> 16);
}

__device__ __forceinline__ float4 ld4(const char* p) { return *(const float4*)p; }

// ---------- weight pack: w[co][c][k] -> B-fragment order, bf16 ----------
// wPack[tap][kk][ct][lane][j] holds B[k=kk*32+(lane>>4)*8+j][co=ct*16+(lane&15)]
__global__ __launch_bounds__(256) void pack_w_kernel(
    const float* __restrict__ w, unsigned short* __restrict__ wPack)
{
    int idx = blockIdx.x * 256 + threadIdx.x;
    if (idx >= KK * 2 * 4 * 64 * 8) return;
    const int j    = idx & 7;
    const int lane = (idx >> 3) & 63;
    const int ct   = (idx >> 9) & 3;
    const int kk   = (idx >> 11) & 1;
    const int tap  = idx >> 12;
    const int c  = kk * 32 + (lane >> 4) * 8 + j;
    const int co = ct * 16 + (lane & 15);
    wPack[idx] = f2bf(w[(co * CIN + c) * KK + tap]);
}

// ---------- x transpose: x[b][c][p] -> xT[b][p][c] (channel-last fp32) ----------
__global__ __launch_bounds__(256) void transpose_x_kernel(
    const float* __restrict__ x, float* __restrict__ xT)
{
    __shared__ float tile[64 * 65];
    const int b  = blockIdx.x / NBLK;
    const int p0 = (blockIdx.x % NBLK) * 64;
    const int tid = threadIdx.x;
    const int lane = tid & 63;
    const int row4 = tid >> 6;
#pragma unroll
    for (int pass = 0; pass < 16; ++pass) {
        const int c = pass * 4 + row4;
        tile[lane * 65 + c] = x[((size_t)b * CIN + c) * PP + p0 + lane];
    }
    __syncthreads();
#pragma unroll
    for (int pass = 0; pass < 16; ++pass) {
        const int pr = pass * 4 + row4;
        xT[((size_t)b * PP + p0 + pr) * 64 + lane] = tile[pr * 65 + lane];
    }
}

// ---------- fused main: fully wave-private tap loop ----------
__global__ __launch_bounds__(256) void deform_mfma_kernel(
    const float* __restrict__ xT, const float* __restrict__ off,
    const unsigned short* __restrict__ wPack, float* __restrict__ out)
{
    __shared__ __align__(16) unsigned short cols[64 * 72]; // [vox][c] bf16, pad 72
    __shared__ int4   oW[4][16][2];   // [wave][band-vox][lo/hi] corner BYTE offsets
    __shared__ float4 wW[4][16][2];   // [wave][band-vox][lo/hi] trilinear weights
    __shared__ float  outb[64 * 65];  // [co][vox]

    const int tid  = threadIdx.x;
    const int wave = tid >> 6;
    const int lane = tid & 63;
    const int bid  = blockIdx.x;
    // XCD-contiguous swizzle: grid 784 = 8 XCDs x 98 tiles
    const int tile = (bid & 7) * 98 + (bid >> 3);
    const int b    = tile / NBLK;
    const int p0   = (tile - b * NBLK) * 64;

    const float* __restrict__ xb   = xT + (size_t)b * PP * 64;
    const char*  __restrict__ xc   = (const char*)xb;
    const float* __restrict__ offb = off + (size_t)b * (3 * KK * PP);

    // geometry lane (lanes 0..15): voxel = wave band + lane
    const int gl = lane & 15;
    const int pv = p0 + wave * 16 + gl;
    const int wq = pv % WWID;
    const int hq = (pv / WWID) % HH;
    const int dq = pv / (HH * WWID);
    const bool geo = (lane < 16);

    const int cq   = lane & 15;   // channel-quad (phase 2) / co col (consume)
    const int vsub = lane >> 4;   // voxel-sub (phase 2) / vox quad (consume)

    f32x4 acc[4];
#pragma unroll
    for (int ct = 0; ct < 4; ++ct) acc[ct] = (f32x4){0.f, 0.f, 0.f, 0.f};

    for (int tap = 0; tap < KK; ++tap) {
        // ---- geometry: lanes 0..15 -> this wave's 16 voxels ----
        if (geo) {
            const int kd = tap / 9, kh = (tap / 3) % 3, kw = tap % 3;
            const float od = offb[(tap * 3 + 0) * PP + pv];
            const float oh = offb[(tap * 3 + 1) * PP + pv];
            const float ow = offb[(tap * 3 + 2) * PP + pv];
            const float pd = od + (float)(dq - 1 + kd);
            const float ph = oh + (float)(hq - 1 + kh);
            const float pw = ow + (float)(wq - 1 + kw);
            const float d0f = floorf(pd), h0f = floorf(ph), w0f = floorf(pw);
            const float fd = pd - d0f, fh = ph - h0f, fw = pw - w0f;
            const int d0 = (int)d0f, h0 = (int)h0f, w0 = (int)w0f;
            const int d1 = d0 + 1, h1 = h0 + 1, w1 = w0 + 1;

            const float wd0 = (1.f - fd) * ((d0 >= 0 && d0 < DD) ? 1.f : 0.f);
            const float wd1 = fd        * ((d1 >= 0 && d1 < DD) ? 1.f : 0.f);
            const float wh0 = (1.f - fh) * ((h0 >= 0 && h0 < HH) ? 1.f : 0.f);
            const float wh1 = fh        * ((h1 >= 0 && h1 < HH) ? 1.f : 0.f);
            const float ww0 = (1.f - fw) * ((w0 >= 0 && w0 < WWID) ? 1.f : 0.f);
            const float ww1 = fw        * ((w1 >= 0 && w1 < WWID) ? 1.f : 0.f);

            const int cd0 = min(max(d0, 0), DD - 1),   cd1 = min(max(d1, 0), DD - 1);
            const int ch0 = min(max(h0, 0), HH - 1),   ch1 = min(max(h1, 0), HH - 1);
            const int cw0 = min(max(w0, 0), WWID - 1), cw1 = min(max(w1, 0), WWID - 1);

            const int r00 = (cd0 * HH + ch0) * WWID;
            const int r01 = (cd0 * HH + ch1) * WWID;
            const int r10 = (cd1 * HH + ch0) * WWID;
            const int r11 = (cd1 * HH + ch1) * WWID;

            // BYTE offsets into channel-last xT (row stride 64 f32 = 256 B)
            oW[wave][gl][0] = make_int4((r00 + cw0) << 8, (r00 + cw1) << 8,
                                        (r01 + cw0) << 8, (r01 + cw1) << 8);
            oW[wave][gl][1] = make_int4((r10 + cw0) << 8, (r10 + cw1) << 8,
                                        (r11 + cw0) << 8, (r11 + cw1) << 8);
            wW[wave][gl][0] = make_float4(wd0 * wh0 * ww0, wd0 * wh0 * ww1,
                                          wd0 * wh1 * ww0, wd0 * wh1 * ww1);
            wW[wave][gl][1] = make_float4(wd1 * wh0 * ww0, wd1 * wh0 * ww1,
                                          wd1 * wh1 * ww0, wd1 * wh1 * ww1);
        }
        // no barrier: all LDS traffic below is wave-private; compiler lgkmcnt
        // orders the write->read within the wave.

        // ---- gather: lane = (vsub, cq); 4 groups cover 16 voxels ----
#pragma unroll
        for (int g = 0; g < 4; ++g) {
            const int v = g * 4 + vsub;                 // band-local voxel
            const int4   oa = oW[wave][v][0];
            const int4   ob = oW[wave][v][1];
            const float4 fa = wW[wave][v][0];
            const float4 fb = wW[wave][v][1];
            const int cb = cq * 16;                     // channel-quad byte off

            const float4 r0 = ld4(xc + (oa.x + cb));
            const float4 r1 = ld4(xc + (oa.y + cb));
            const float4 r2 = ld4(xc + (oa.z + cb));
            const float4 r3 = ld4(xc + (oa.w + cb));
            const float4 r4 = ld4(xc + (ob.x + cb));
            const float4 r5 = ld4(xc + (ob.y + cb));
            const float4 r6 = ld4(xc + (ob.z + cb));
            const float4 r7 = ld4(xc + (ob.w + cb));

            float4 vv;
            vv.x = fa.x*r0.x + fa.y*r1.x + fa.z*r2.x + fa.w*r3.x
                 + fb.x*r4.x + fb.y*r5.x + fb.z*r6.x + fb.w*r7.x;
            vv.y = fa.x*r0.y + fa.y*r1.y + fa.z*r2.y + fa.w*r3.y
                 + fb.x*r4.y + fb.y*r5.y + fb.z*r6.y + fb.w*r7.y;
            vv.z = fa.x*r0.z + fa.y*r1.z + fa.z*r2.z + fa.w*r3.z
                 + fb.x*r4.z + fb.y*r5.z + fb.z*r6.z + fb.w*r7.z;
            vv.w = fa.x*r0.w + fa.y*r1.w + fa.z*r2.w + fa.w*r3.w
                 + fb.x*r4.w + fb.y*r5.w + fb.z*r6.w + fb.w*r7.w;

            u16x4 pk;
            pk.x = f2bf(vv.x); pk.y = f2bf(vv.y);
            pk.z = f2bf(vv.z); pk.w = f2bf(vv.w);
            // byte addr = (wave*16+v)*144 + cq*8 : 8B-aligned, wave-private row
            *(u16x4*)(cols + (wave * 16 + v) * 72 + cq * 4) = pk;
        }

        // ---- consume: wave w: vox band [16w,16w+16) x all 64 co ----
#pragma unroll
        for (int kk = 0; kk < 2; ++kk) {
            const bf16x8 afrag = *(const bf16x8*)
                (cols + (wave * 16 + cq) * 72 + kk * 32 + vsub * 8);
            const bf16x8* wp = (const bf16x8*)
                (wPack + (size_t)(tap * 2 + kk) * 4 * 64 * 8);
#pragma unroll
            for (int ct = 0; ct < 4; ++ct) {
                const bf16x8 bfrag = wp[ct * 64 + lane];
                acc[ct] = __builtin_amdgcn_mfma_f32_16x16x32_bf16(
                    afrag, bfrag, acc[ct], 0, 0, 0);
            }
        }
    }

    // ---- epilogue: C/D layout col=lane&15 (co), row=(lane>>4)*4+reg (vox) ----
#pragma unroll
    for (int ct = 0; ct < 4; ++ct) {
#pragma unroll
        for (int reg = 0; reg < 4; ++reg) {
            const int vox = wave * 16 + vsub * 4 + reg;
            const int co  = ct * 16 + cq;
            outb[co * 65 + vox] = acc[ct][reg];
        }
    }
    __syncthreads();

#pragma unroll
    for (int i = 0; i < 16; ++i) {
        const int co = wave * 16 + i;
        out[((size_t)b * COUT + co) * PP + p0 + lane] = outb[co * 65 + lane];
    }
}

// ---------- fallback if ws too small ----------
__global__ __launch_bounds__(128) void deform_fallback_kernel(
    const float* __restrict__ x, const float* __restrict__ off,
    const float* __restrict__ w, float* __restrict__ out)
{
    const int co_half = blockIdx.x / 392;
    const int vox     = (blockIdx.x % 392) * 128 + threadIdx.x;
    const int b  = vox / PP;
    const int p  = vox - b * PP;
    const int wq = p % WWID;
    const int hq = (p / WWID) % HH;
    const int dq = p / (HH * WWID);
    const int co_base = co_half * 32;
    const float* xb   = x + (size_t)b * (CIN * PP);
    const float* offb = off + (size_t)b * (3 * KK * PP) + p;
    float acc[32];
#pragma unroll
    for (int j = 0; j < 32; ++j) acc[j] = 0.f;
    for (int k = 0; k < KK; ++k) {
        const int kd = k / 9, kh = (k / 3) % 3, kw = k % 3;
        const float od = offb[(k * 3 + 0) * PP];
        const float oh = offb[(k * 3 + 1) * PP];
        const float ow = offb[(k * 3 + 2) * PP];
        const float pd = od + (float)(dq - 1 + kd);
        const float ph = oh + (float)(hq - 1 + kh);
        const float pw = ow + (float)(wq - 1 + kw);
        const float d0f = floorf(pd), h0f = floorf(ph), w0f = floorf(pw);
        const float fd = pd - d0f, fh = ph - h0f, fw = pw - w0f;
        const int d0 = (int)d0f, h0 = (int)h0f, w0 = (int)w0f;
        const int d1 = d0 + 1, h1 = h0 + 1, w1 = w0 + 1;
        const float wd0 = (1.f - fd) * ((d0 >= 0 && d0 < DD) ? 1.f : 0.f);
        const float wd1 = fd        * ((d1 >= 0 && d1 < DD) ? 1.f : 0.f);
        const float wh0 = (1.f - fh) * ((h0 >= 0 && h0 < HH) ? 1.f : 0.f);
        const float wh1 = fh        * ((h1 >= 0 && h1 < HH) ? 1.f : 0.f);
        const float ww0 = (1.f - fw) * ((w0 >= 0 && w0 < WWID) ? 1.f : 0.f);
        const float ww1 = fw        * ((w1 >= 0 && w1 < WWID) ? 1.f : 0.f);
        const int cd0 = min(max(d0, 0), DD - 1),   cd1 = min(max(d1, 0), DD - 1);
        const int ch0 = min(max(h0, 0), HH - 1),   ch1 = min(max(h1, 0), HH - 1);
        const int cw0 = min(max(w0, 0), WWID - 1), cw1 = min(max(w1, 0), WWID - 1);
        const int l000 = (cd0 * HH + ch0) * WWID + cw0;
        const int l001 = (cd0 * HH + ch0) * WWID + cw1;
        const int l010 = (cd0 * HH + ch1) * WWID + cw0;
        const int l011 = (cd0 * HH + ch1) * WWID + cw1;
        const int l100 = (cd1 * HH + ch0) * WWID + cw0;
        const int l101 = (cd1 * HH + ch0) * WWID + cw1;
        const int l110 = (cd1 * HH + ch1) * WWID + cw0;
        const int l111 = (cd1 * HH + ch1) * WWID + cw1;
        const float c000 = wd0 * wh0 * ww0, c001 = wd0 * wh0 * ww1;
        const float c010 = wd0 * wh1 * ww0, c011 = wd0 * wh1 * ww1;
        const float c100 = wd1 * wh0 * ww0, c101 = wd1 * wh0 * ww1;
        const float c110 = wd1 * wh1 * ww0, c111 = wd1 * wh1 * ww1;
        for (int c = 0; c < CIN; ++c) {
            const float* xcp = xb + (size_t)c * PP;
            float v = c000 * xcp[l000] + c001 * xcp[l001]
                    + c010 * xcp[l010] + c011 * xcp[l011]
                    + c100 * xcp[l100] + c101 * xcp[l101]
                    + c110 * xcp[l110] + c111 * xcp[l111];
#pragma unroll
            for (int j = 0; j < 32; ++j)
                acc[j] += w[((size_t)(co_base + j) * CIN + c) * KK + k] * v;
        }
    }
    float* ob = out + (size_t)b * (COUT * PP) + (size_t)co_base * PP + p;
#pragma unroll
    for (int j = 0; j < 32; ++j) ob[j * PP] = acc[j];
}

extern "C" void kernel_launch(void* const* d_in, const int* in_sizes, int n_in,
                              void* d_out, int out_size, void* d_ws, size_t ws_size,
                              hipStream_t stream)
{
    const float* x   = (const float*)d_in[0];
    const float* off = (const float*)d_in[1];
    const float* w   = (const float*)d_in[2];
    float* out = (float*)d_out;

    const size_t xt_bytes = (size_t)BB * PP * CIN * sizeof(float);      // 12,845,056
    const size_t wp_elems = (size_t)KK * 2 * 4 * 64 * 8;                // 110,592
    const size_t need = xt_bytes + wp_elems * sizeof(unsigned short);

    if (ws_size >= need) {
        float* xT = (float*)d_ws;
        unsigned short* wPack = (unsigned short*)((char*)d_ws + xt_bytes);
        pack_w_kernel<<<(int)((wp_elems + 255) / 256), 256, 0, stream>>>(w, wPack);
        transpose_x_kernel<<<BB * NBLK, 256, 0, stream>>>(x, xT);
        deform_mfma_kernel<<<BB * NBLK, 256, 0, stream>>>(xT, off, wPack, out);
    } else {
        deform_fallback_kernel<<<2 * 392, 128, 0, stream>>>(x, off, w, out);
    }
}

// Round 6
// 213.311 us; speedup vs baseline: 12.5738x; 1.1964x over previous
//
#include <hip/hip_runtime.h>

// DeformConv3D forward. B=2, C=Cout=64, D=8, H=56, W=56, K=27,
// stride=pad=dil=1, dg=1, groups=1. Fused interp + bf16 MFMA GEMM.
// R6: 3-way tap split (grid 2352, atomicAdd epilogue onto zeroed out) +
//     LDS overlay (16.6 KB) -> full 32-waves/CU occupancy for latency hiding.
#define CIN  64
#define COUT 64
#define DD   8
#define HH   56
#define WWID 56
#define KK   27
#define PP   (DD * HH * WWID)   // 25088
#define BB   2
#define NBLK 392                // PP/64 voxel tiles per batch
#define NSEG 3                  // tap segments (9 taps each)

typedef float  f32x4  __attribute__((ext_vector_type(4)));
typedef __bf16 bf16x8 __attribute__((ext_vector_type(8)));
typedef unsigned short u16x4 __attribute__((ext_vector_type(4)));

__device__ __forceinline__ unsigned short f2bf(float f) {
    union { float f; unsigned u; } v; v.f = f;
    unsigned r = v.u + 0x7FFF + ((v.u >> 16) & 1);   // RNE
    return (unsigned short)(r >> 16);
}

__device__ __forceinline__ float4 ld4(const char* p) { return *(const float4*)p; }

// ---------- weight pack: w[co][c][k] -> B-fragment order, bf16 ----------
// wPack[tap][kk][ct][lane][j] holds B[k=kk*32+(lane>>4)*8+j][co=ct*16+(lane&15)]
__global__ __launch_bounds__(256) void pack_w_kernel(
    const float* __restrict__ w, unsigned short* __restrict__ wPack)
{
    int idx = blockIdx.x * 256 + threadIdx.x;
    if (idx >= KK * 2 * 4 * 64 * 8) return;
    const int j    = idx & 7;
    const int lane = (idx >> 3) & 63;
    const int ct   = (idx >> 9) & 3;
    const int kk   = (idx >> 11) & 1;
    const int tap  = idx >> 12;
    const int c  = kk * 32 + (lane >> 4) * 8 + j;
    const int co = ct * 16 + (lane & 15);
    wPack[idx] = f2bf(w[(co * CIN + c) * KK + tap]);
}

// ---------- x transpose: x[b][c][p] -> xT[b][p][c] (channel-last fp32) ----------
__global__ __launch_bounds__(256) void transpose_x_kernel(
    const float* __restrict__ x, float* __restrict__ xT)
{
    __shared__ float tile[64 * 65];
    const int b  = blockIdx.x / NBLK;
    const int p0 = (blockIdx.x % NBLK) * 64;
    const int tid = threadIdx.x;
    const int lane = tid & 63;
    const int row4 = tid >> 6;
#pragma unroll
    for (int pass = 0; pass < 16; ++pass) {
        const int c = pass * 4 + row4;
        tile[lane * 65 + c] = x[((size_t)b * CIN + c) * PP + p0 + lane];
    }
    __syncthreads();
#pragma unroll
    for (int pass = 0; pass < 16; ++pass) {
        const int pr = pass * 4 + row4;
        xT[((size_t)b * PP + p0 + pr) * 64 + lane] = tile[pr * 65 + lane];
    }
}

// ---------- fused main: wave-private tap loop over one 9-tap segment ----------
__global__ __launch_bounds__(256) void deform_mfma_kernel(
    const float* __restrict__ xT, const float* __restrict__ off,
    const unsigned short* __restrict__ wPack, float* __restrict__ out)
{
    // overlay arena: loop phase uses cols(9216)+oW(2048)+wW(2048)=13312 B,
    // epilogue reuses it as outb (64*65*4 = 16640 B). Max 16640.
    __shared__ __align__(16) char smem[16640];
    unsigned short* cols = (unsigned short*)smem;          // [64][72] bf16
    int4*   oW = (int4*)(smem + 9216);                     // [wave*16+gl][2]
    float4* wW = (float4*)(smem + 9216 + 2048);            // [wave*16+gl][2]
    float*  outb = (float*)smem;                           // [co][65] epilogue

    const int tid  = threadIdx.x;
    const int wave = tid >> 6;
    const int lane = tid & 63;
    const int bid  = blockIdx.x;
    // grid 2352 = 8 XCDs x (98 tiles x 3 segs); same tile -> same XCD.
    const int xcd  = bid & 7;
    const int idx  = bid >> 3;            // 0..293
    const int tile = xcd * 98 + (idx % 98);
    const int seg  = idx / 98;            // 0..2
    const int tap0 = seg * 9;
    const int b    = tile / NBLK;
    const int p0   = (tile - b * NBLK) * 64;

    const float* __restrict__ xb   = xT + (size_t)b * PP * 64;
    const char*  __restrict__ xc   = (const char*)xb;
    const float* __restrict__ offb = off + (size_t)b * (3 * KK * PP);

    // geometry lane (lanes 0..15): voxel = wave band + lane
    const int gl = lane & 15;
    const int pv = p0 + wave * 16 + gl;
    const int wq = pv % WWID;
    const int hq = (pv / WWID) % HH;
    const int dq = pv / (HH * WWID);
    const bool geo = (lane < 16);

    const int cq   = lane & 15;   // channel-quad (gather) / co col (consume)
    const int vsub = lane >> 4;   // voxel-sub (gather) / vox quad (consume)

    f32x4 acc[4];
#pragma unroll
    for (int ct = 0; ct < 4; ++ct) acc[ct] = (f32x4){0.f, 0.f, 0.f, 0.f};

    for (int tap = tap0; tap < tap0 + 9; ++tap) {
        // ---- geometry: lanes 0..15 -> this wave's 16 voxels ----
        if (geo) {
            const int kd = tap / 9, kh = (tap / 3) % 3, kw = tap % 3;
            const float od = offb[(tap * 3 + 0) * PP + pv];
            const float oh = offb[(tap * 3 + 1) * PP + pv];
            const float ow = offb[(tap * 3 + 2) * PP + pv];
            const float pd = od + (float)(dq - 1 + kd);
            const float ph = oh + (float)(hq - 1 + kh);
            const float pw = ow + (float)(wq - 1 + kw);
            const float d0f = floorf(pd), h0f = floorf(ph), w0f = floorf(pw);
            const float fd = pd - d0f, fh = ph - h0f, fw = pw - w0f;
            const int d0 = (int)d0f, h0 = (int)h0f, w0 = (int)w0f;
            const int d1 = d0 + 1, h1 = h0 + 1, w1 = w0 + 1;

            const float wd0 = (1.f - fd) * ((d0 >= 0 && d0 < DD) ? 1.f : 0.f);
            const float wd1 = fd        * ((d1 >= 0 && d1 < DD) ? 1.f : 0.f);
            const float wh0 = (1.f - fh) * ((h0 >= 0 && h0 < HH) ? 1.f : 0.f);
            const float wh1 = fh        * ((h1 >= 0 && h1 < HH) ? 1.f : 0.f);
            const float ww0 = (1.f - fw) * ((w0 >= 0 && w0 < WWID) ? 1.f : 0.f);
            const float ww1 = fw        * ((w1 >= 0 && w1 < WWID) ? 1.f : 0.f);

            const int cd0 = min(max(d0, 0), DD - 1),   cd1 = min(max(d1, 0), DD - 1);
            const int ch0 = min(max(h0, 0), HH - 1),   ch1 = min(max(h1, 0), HH - 1);
            const int cw0 = min(max(w0, 0), WWID - 1), cw1 = min(max(w1, 0), WWID - 1);

            const int r00 = (cd0 * HH + ch0) * WWID;
            const int r01 = (cd0 * HH + ch1) * WWID;
            const int r10 = (cd1 * HH + ch0) * WWID;
            const int r11 = (cd1 * HH + ch1) * WWID;

            const int gi = (wave * 16 + gl) * 2;
            oW[gi + 0] = make_int4((r00 + cw0) << 8, (r00 + cw1) << 8,
                                   (r01 + cw0) << 8, (r01 + cw1) << 8);
            oW[gi + 1] = make_int4((r10 + cw0) << 8, (r10 + cw1) << 8,
                                   (r11 + cw0) << 8, (r11 + cw1) << 8);
            wW[gi + 0] = make_float4(wd0 * wh0 * ww0, wd0 * wh0 * ww1,
                                     wd0 * wh1 * ww0, wd0 * wh1 * ww1);
            wW[gi + 1] = make_float4(wd1 * wh0 * ww0, wd1 * wh0 * ww1,
                                     wd1 * wh1 * ww0, wd1 * wh1 * ww1);
        }
        // wave-private LDS; compiler lgkmcnt orders write->read within wave.

        // ---- gather: lane = (vsub, cq); 4 groups cover the 16 voxels ----
#pragma unroll
        for (int g = 0; g < 4; ++g) {
            const int v = g * 4 + vsub;                 // band-local voxel
            const int gi = (wave * 16 + v) * 2;
            const int4   oa = oW[gi + 0];
            const int4   ob = oW[gi + 1];
            const float4 fa = wW[gi + 0];
            const float4 fb = wW[gi + 1];
            const int cb = cq * 16;                     // channel-quad byte off

            const float4 r0 = ld4(xc + (oa.x + cb));
            const float4 r1 = ld4(xc + (oa.y + cb));
            const float4 r2 = ld4(xc + (oa.z + cb));
            const float4 r3 = ld4(xc + (oa.w + cb));
            const float4 r4 = ld4(xc + (ob.x + cb));
            const float4 r5 = ld4(xc + (ob.y + cb));
            const float4 r6 = ld4(xc + (ob.z + cb));
            const float4 r7 = ld4(xc + (ob.w + cb));

            float4 vv;
            vv.x = fa.x*r0.x + fa.y*r1.x + fa.z*r2.x + fa.w*r3.x
                 + fb.x*r4.x + fb.y*r5.x + fb.z*r6.x + fb.w*r7.x;
            vv.y = fa.x*r0.y + fa.y*r1.y + fa.z*r2.y + fa.w*r3.y
                 + fb.x*r4.y + fb.y*r5.y + fb.z*r6.y + fb.w*r7.y;
            vv.z = fa.x*r0.z + fa.y*r1.z + fa.z*r2.z + fa.w*r3.z
                 + fb.x*r4.z + fb.y*r5.z + fb.z*r6.z + fb.w*r7.z;
            vv.w = fa.x*r0.w + fa.y*r1.w + fa.z*r2.w + fa.w*r3.w
                 + fb.x*r4.w + fb.y*r5.w + fb.z*r6.w + fb.w*r7.w;

            u16x4 pk;
            pk.x = f2bf(vv.x); pk.y = f2bf(vv.y);
            pk.z = f2bf(vv.z); pk.w = f2bf(vv.w);
            *(u16x4*)(cols + (wave * 16 + v) * 72 + cq * 4) = pk;
        }

        // ---- consume: wave w: vox band [16w,16w+16) x all 64 co ----
#pragma unroll
        for (int kk = 0; kk < 2; ++kk) {
            const bf16x8 afrag = *(const bf16x8*)
                (cols + (wave * 16 + cq) * 72 + kk * 32 + vsub * 8);
            const bf16x8* wp = (const bf16x8*)
                (wPack + (size_t)(tap * 2 + kk) * 4 * 64 * 8);
#pragma unroll
            for (int ct = 0; ct < 4; ++ct) {
                const bf16x8 bfrag = wp[ct * 64 + lane];
                acc[ct] = __builtin_amdgcn_mfma_f32_16x16x32_bf16(
                    afrag, bfrag, acc[ct], 0, 0, 0);
            }
        }
    }

    // ---- epilogue: overlay smem as outb; all waves must exit loop first ----
    __syncthreads();
#pragma unroll
    for (int ct = 0; ct < 4; ++ct) {
#pragma unroll
        for (int reg = 0; reg < 4; ++reg) {
            const int vox = wave * 16 + vsub * 4 + reg;
            const int co  = ct * 16 + cq;
            outb[co * 65 + vox] = acc[ct][reg];
        }
    }
    __syncthreads();

#pragma unroll
    for (int i = 0; i < 16; ++i) {
        const int co = wave * 16 + i;
        atomicAdd(&out[((size_t)b * COUT + co) * PP + p0 + lane],
                  outb[co * 65 + lane]);
    }
}

// ---------- fallback if ws too small (writes out directly, no split) ----------
__global__ __launch_bounds__(128) void deform_fallback_kernel(
    const float* __restrict__ x, const float* __restrict__ off,
    const float* __restrict__ w, float* __restrict__ out)
{
    const int co_half = blockIdx.x / 392;
    const int vox     = (blockIdx.x % 392) * 128 + threadIdx.x;
    const int b  = vox / PP;
    const int p  = vox - b * PP;
    const int wq = p % WWID;
    const int hq = (p / WWID) % HH;
    const int dq = p / (HH * WWID);
    const int co_base = co_half * 32;
    const float* xb   = x + (size_t)b * (CIN * PP);
    const float* offb = off + (size_t)b * (3 * KK * PP) + p;
    float acc[32];
#pragma unroll
    for (int j = 0; j < 32; ++j) acc[j] = 0.f;
    for (int k = 0; k < KK; ++k) {
        const int kd = k / 9, kh = (k / 3) % 3, kw = k % 3;
        const float od = offb[(k * 3 + 0) * PP];
        const float oh = offb[(k * 3 + 1) * PP];
        const float ow = offb[(k * 3 + 2) * PP];
        const float pd = od + (float)(dq - 1 + kd);
        const float ph = oh + (float)(hq - 1 + kh);
        const float pw = ow + (float)(wq - 1 + kw);
        const float d0f = floorf(pd), h0f = floorf(ph), w0f = floorf(pw);
        const float fd = pd - d0f, fh = ph - h0f, fw = pw - w0f;
        const int d0 = (int)d0f, h0 = (int)h0f, w0 = (int)w0f;
        const int d1 = d0 + 1, h1 = h0 + 1, w1 = w0 + 1;
        const float wd0 = (1.f - fd) * ((d0 >= 0 && d0 < DD) ? 1.f : 0.f);
        const float wd1 = fd        * ((d1 >= 0 && d1 < DD) ? 1.f : 0.f);
        const float wh0 = (1.f - fh) * ((h0 >= 0 && h0 < HH) ? 1.f : 0.f);
        const float wh1 = fh        * ((h1 >= 0 && h1 < HH) ? 1.f : 0.f);
        const float ww0 = (1.f - fw) * ((w0 >= 0 && w0 < WWID) ? 1.f : 0.f);
        const float ww1 = fw        * ((w1 >= 0 && w1 < WWID) ? 1.f : 0.f);
        const int cd0 = min(max(d0, 0), DD - 1),   cd1 = min(max(d1, 0), DD - 1);
        const int ch0 = min(max(h0, 0), HH - 1),   ch1 = min(max(h1, 0), HH - 1);
        const int cw0 = min(max(w0, 0), WWID - 1), cw1 = min(max(w1, 0), WWID - 1);
        const int l000 = (cd0 * HH + ch0) * WWID + cw0;
        const int l001 = (cd0 * HH + ch0) * WWID + cw1;
        const int l010 = (cd0 * HH + ch1) * WWID + cw0;
        const int l011 = (cd0 * HH + ch1) * WWID + cw1;
        const int l100 = (cd1 * HH + ch0) * WWID + cw0;
        const int l101 = (cd1 * HH + ch0) * WWID + cw1;
        const int l110 = (cd1 * HH + ch1) * WWID + cw0;
        const int l111 = (cd1 * HH + ch1) * WWID + cw1;
        const float c000 = wd0 * wh0 * ww0, c001 = wd0 * wh0 * ww1;
        const float c010 = wd0 * wh1 * ww0, c011 = wd0 * wh1 * ww1;
        const float c100 = wd1 * wh0 * ww0, c101 = wd1 * wh0 * ww1;
        const float c110 = wd1 * wh1 * ww0, c111 = wd1 * wh1 * ww1;
        for (int c = 0; c < CIN; ++c) {
            const float* xcp = xb + (size_t)c * PP;
            float v = c000 * xcp[l000] + c001 * xcp[l001]
                    + c010 * xcp[l010] + c011 * xcp[l011]
                    + c100 * xcp[l100] + c101 * xcp[l101]
                    + c110 * xcp[l110] + c111 * xcp[l111];
#pragma unroll
            for (int j = 0; j < 32; ++j)
                acc[j] += w[((size_t)(co_base + j) * CIN + c) * KK + k] * v;
        }
    }
    float* ob = out + (size_t)b * (COUT * PP) + (size_t)co_base * PP + p;
#pragma unroll
    for (int j = 0; j < 32; ++j) ob[j * PP] = acc[j];
}

extern "C" void kernel_launch(void* const* d_in, const int* in_sizes, int n_in,
                              void* d_out, int out_size, void* d_ws, size_t ws_size,
                              hipStream_t stream)
{
    const float* x   = (const float*)d_in[0];
    const float* off = (const float*)d_in[1];
    const float* w   = (const float*)d_in[2];
    float* out = (float*)d_out;

    const size_t xt_bytes = (size_t)BB * PP * CIN * sizeof(float);      // 12,845,056
    const size_t wp_elems = (size_t)KK * 2 * 4 * 64 * 8;                // 110,592
    const size_t need = xt_bytes + wp_elems * sizeof(unsigned short);

    if (ws_size >= need) {
        float* xT = (float*)d_ws;
        unsigned short* wPack = (unsigned short*)((char*)d_ws + xt_bytes);
        hipMemsetAsync(d_out, 0, (size_t)out_size * sizeof(float), stream);
        pack_w_kernel<<<(int)((wp_elems + 255) / 256), 256, 0, stream>>>(w, wPack);
        transpose_x_kernel<<<BB * NBLK, 256, 0, stream>>>(x, xT);
        deform_mfma_kernel<<<8 * 98 * NSEG, 256, 0, stream>>>(xT, off, wPack, out);
    } else {
        deform_fallback_kernel<<<2 * 392, 128, 0, stream>>>(x, off, w, out);
    }
}